// Round 10
// baseline (1673.296 us; speedup 1.0000x reference)
//
#include <hip/hip_runtime.h>
#include <hip/hip_bf16.h>

#define N_NODES   50000
#define N_EDGES   600000
#define F         128
#define N_GRAPHS  64
#define N_CLASSES 10
#define NPAD      50048           // multiple of 64
#define NB_SCAN   196             // ceil(50000/256)
#define XCVT_BLOCKS 6250          // N_NODES*F/4/256
#define WCVT_BLOCKS 96            // 6*F*F/4/256
#define EDGE_BLOCKS 2344          // ceil(N_EDGES/256)

typedef __attribute__((ext_vector_type(8))) short bf16x8;
typedef __attribute__((ext_vector_type(4))) float f32x4;

static __device__ __forceinline__ unsigned short f2bf(float f) {
    __hip_bfloat16 h = __float2bfloat16(f);
    return *reinterpret_cast<unsigned short*>(&h);
}
static __device__ __forceinline__ float bf2f(unsigned short u) {
    return __uint_as_float(((unsigned)u) << 16);
}

// ================= prep: x->bf16, W->bf16, degree histogram — ONE dispatch =================
__global__ __launch_bounds__(256) void prep_kernel(
    const float* __restrict__ x,
    const float* __restrict__ W0, const float* __restrict__ W1,
    const float* __restrict__ W2, const float* __restrict__ W3,
    const float* __restrict__ W4, const float* __restrict__ W5,
    const int* __restrict__ dst,
    unsigned short* __restrict__ Xb, unsigned short* __restrict__ Wb,
    int* __restrict__ deg)
{
    int b = blockIdx.x;
    if (b < XCVT_BLOCKS) {
        int i = b * 256 + threadIdx.x;
        float4 v = reinterpret_cast<const float4*>(x)[i];
        ushort4 o;
        o.x = f2bf(v.x); o.y = f2bf(v.y); o.z = f2bf(v.z); o.w = f2bf(v.w);
        reinterpret_cast<ushort4*>(Xb)[i] = o;
    } else if (b < XCVT_BLOCKS + WCVT_BLOCKS) {
        const int PER = (F * F / 4) / 256;   // 16
        int bb  = b - XCVT_BLOCKS;
        int mat = bb / PER;
        int i   = (bb % PER) * 256 + threadIdx.x;
        const float* W = (mat == 0) ? W0 : (mat == 1) ? W1 : (mat == 2) ? W2
                       : (mat == 3) ? W3 : (mat == 4) ? W4 : W5;
        float4 v = reinterpret_cast<const float4*>(W)[i];
        ushort4 o;
        o.x = f2bf(v.x); o.y = f2bf(v.y); o.z = f2bf(v.z); o.w = f2bf(v.w);
        reinterpret_cast<ushort4*>(Wb + (size_t)mat * F * F)[i] = o;
    } else {
        int e = (b - XCVT_BLOCKS - WCVT_BLOCKS) * 256 + threadIdx.x;
        if (e < N_EDGES) atomicAdd(&deg[dst[e]], 1);
    }
}

// ---- hierarchical scan ----
__global__ __launch_bounds__(256) void scanA_kernel(
    const int* __restrict__ deg, int* __restrict__ locEx, int* __restrict__ blockSum)
{
    __shared__ int sh[256];
    int t = threadIdx.x;
    int idx = blockIdx.x * 256 + t;
    int v = (idx < N_NODES) ? deg[idx] : 0;
    sh[t] = v;
    __syncthreads();
#pragma unroll
    for (int d = 1; d < 256; d <<= 1) {
        int u = (t >= d) ? sh[t - d] : 0;
        __syncthreads();
        sh[t] += u;
        __syncthreads();
    }
    if (idx < N_NODES) locEx[idx] = sh[t] - v;
    if (t == 255) blockSum[blockIdx.x] = sh[255];
}

__global__ __launch_bounds__(256) void scanBC_kernel(
    const int* __restrict__ locEx, const int* __restrict__ blockSum,
    int* __restrict__ off)
{
    __shared__ int sh[256];
    int t = threadIdx.x;
    int v = (t < NB_SCAN) ? blockSum[t] : 0;
    sh[t] = v;
    __syncthreads();
#pragma unroll
    for (int d = 1; d < 256; d <<= 1) {
        int u = (t >= d) ? sh[t - d] : 0;
        __syncthreads();
        sh[t] += u;
        __syncthreads();
    }
    int myVal = blockSum[blockIdx.x];
    int base  = sh[blockIdx.x] - myVal;
    int idx = blockIdx.x * 256 + t;
    if (idx < N_NODES) off[idx] = locEx[idx] + base;
    if (blockIdx.x == 0 && t == 0) off[N_NODES] = sh[NB_SCAN - 1];
}

// fill packed compact CSR: entry = (src<<6) | (dst & 63)
__global__ __launch_bounds__(256) void fillP_kernel(
    const int* __restrict__ src, const int* __restrict__ dst,
    const int* __restrict__ off, int* __restrict__ cursor,
    int* __restrict__ csrP)
{
    int e = blockIdx.x * 256 + threadIdx.x;
    if (e >= N_EDGES) return;
    int d = dst[e];
    int slot = atomicAdd(&cursor[d], 1);
    csrP[off[d] + slot] = (src[e] << 6) | (d & 63);
}

// ================= fused gather + GraphConv via MFMA =================
// Phase 1: EDGE-PARALLEL gather — block's edges are one contiguous csrP
//          segment; 8 threads/edge x 16 feats; fp32 LDS accumulation via
//          ds_add_f32 into a bank-XOR-swizzled tile (no divergence, deep MLP).
// Phase 1.5: in-place fp32 -> bf16 (reg-staged, barrier) into swizzled layout.
// Phase 2: H = [relu](AGG@Wrel^T + b + X@Wroot^T), 4 waves 2x2, tile 32x64.
template <int RELU>
__global__ __launch_bounds__(256) void conv_fused(
    const unsigned short* __restrict__ Xb,
    const int* __restrict__ off, const int* __restrict__ csrP,
    const unsigned short* __restrict__ Wrel, const unsigned short* __restrict__ Wroot,
    const float* __restrict__ brel, unsigned short* __restrict__ H)
{
    __shared__ float Af[64 * 128];                 // 32 KB fp32 accum tile
    char* AsRaw = reinterpret_cast<char*>(Af);     // low 16 KB reused as bf16
    const int t = threadIdx.x;
    const int mBase = blockIdx.x * 64;

    // zero accumulators
#pragma unroll
    for (int i = 0; i < 32; ++i) Af[t + i * 256] = 0.f;
    __syncthreads();

    // ---- phase 1: edge-parallel gather ----
    {
        int rowEnd = mBase + 64; if (rowEnd > N_NODES) rowEnd = N_NODES;
        const int e0 = off[mBase];
        const int nW = (off[rowEnd] - e0) * 8;     // 8 threads per edge
        for (int w = t; w < nW; w += 256) {
            int j = w >> 3, q = w & 7;
            int pk = csrP[e0 + j];
            int s = pk >> 6, r = pk & 63;
            const bf16x8* ps = reinterpret_cast<const bf16x8*>(
                Xb + (size_t)s * F + q * 16);
            bf16x8 v0 = ps[0], v1 = ps[1];
            int fb = q * 16;
            int sw = (r & 7) << 2;                 // element-granular XOR (16B units)
            float* Ar = Af + r * F;
#pragma unroll
            for (int i = 0; i < 8; ++i)
                unsafeAtomicAdd(&Ar[(fb + i) ^ sw], bf2f((unsigned short)v0[i]));
#pragma unroll
            for (int i = 0; i < 8; ++i)
                unsafeAtomicAdd(&Ar[(fb + 8 + i) ^ sw], bf2f((unsigned short)v1[i]));
        }
    }
    __syncthreads();

    // ---- phase 1.5: fp32 -> bf16 in place (reg-staged) ----
    {
        int r  = t >> 2;
        int f0 = (t & 3) * 32;
        int sw = (r & 7) << 2;
        float* Ar = Af + r * F;
        float vals[32];
#pragma unroll
        for (int c = 0; c < 8; ++c) {
            float4 v = *reinterpret_cast<const float4*>(&Ar[(f0 + c * 4) ^ sw]);
            vals[c * 4 + 0] = v.x; vals[c * 4 + 1] = v.y;
            vals[c * 4 + 2] = v.z; vals[c * 4 + 3] = v.w;
        }
        __syncthreads();                            // all fp32 staged in regs
        int swb = (r & 7) << 4;                     // byte-granular XOR for bf16
#pragma unroll
        for (int c = 0; c < 4; ++c) {
            bf16x8 o;
#pragma unroll
            for (int e = 0; e < 8; ++e) o[e] = (short)f2bf(vals[c * 8 + e]);
            int bytecol = ((f0 + c * 8) * 2) ^ swb;
            *reinterpret_cast<bf16x8*>(AsRaw + r * 256 + bytecol) = o;
        }
    }
    __syncthreads();

    // ---- phase 2: MFMA, 4 waves in 2x2, wave tile 32x64 ----
    const int wave = t >> 6;
    const int lane = t & 63;
    const int wm = wave >> 1, wn = wave & 1;
    const int m0l = wm * 32;
    const int n0  = wn * 64;
    const int lrow = lane & 15;
    const int lk8  = (lane >> 4) << 3;

    f32x4 acc[2][4];
#pragma unroll
    for (int mi = 0; mi < 2; ++mi)
#pragma unroll
        for (int ni = 0; ni < 4; ++ni)
            acc[mi][ni] = (f32x4){0.f, 0.f, 0.f, 0.f};

#pragma unroll
    for (int p = 0; p < 2; ++p) {
        const unsigned short* W = p ? Wroot : Wrel;
#pragma unroll
        for (int ks = 0; ks < 4; ++ks) {
            int k0 = ks * 32 + lk8;
            bf16x8 a[2], b[4];
#pragma unroll
            for (int mi = 0; mi < 2; ++mi) {
                int rl = m0l + mi * 16 + lrow;
                if (p == 0) {
                    int bytecol = (k0 * 2) ^ ((rl & 7) << 4);
                    a[mi] = *reinterpret_cast<const bf16x8*>(AsRaw + rl * 256 + bytecol);
                } else {
                    a[mi] = *reinterpret_cast<const bf16x8*>(
                        Xb + (size_t)(mBase + rl) * F + k0);
                }
            }
#pragma unroll
            for (int ni = 0; ni < 4; ++ni)
                b[ni] = *reinterpret_cast<const bf16x8*>(
                    W + (size_t)(n0 + ni * 16 + lrow) * F + k0);
#pragma unroll
            for (int mi = 0; mi < 2; ++mi)
#pragma unroll
                for (int ni = 0; ni < 4; ++ni)
                    acc[mi][ni] = __builtin_amdgcn_mfma_f32_16x16x32_bf16(
                        a[mi], b[ni], acc[mi][ni], 0, 0, 0);
        }
    }

    const int r0 = (lane >> 4) << 2;   // C/D: row = (lane>>4)*4 + reg
#pragma unroll
    for (int ni = 0; ni < 4; ++ni) {
        int col = n0 + ni * 16 + lrow;
        float bb = brel[col];
#pragma unroll
        for (int mi = 0; mi < 2; ++mi) {
#pragma unroll
            for (int r = 0; r < 4; ++r) {
                int row = mBase + m0l + mi * 16 + r0 + r;
                if (row < N_NODES) {
                    float v = acc[mi][ni][r] + bb;
                    if (RELU) v = fmaxf(v, 0.f);
                    H[(size_t)row * F + col] = f2bf(v);
                }
            }
        }
    }
}

// ================= mean pool + classifier head fused =================
__global__ __launch_bounds__(256) void poolhead_kernel(
    const unsigned short* __restrict__ H, const int* __restrict__ batch,
    const float* __restrict__ Wl, const float* __restrict__ bl,
    float* __restrict__ out)
{
    int g = blockIdx.x;
    int lo = 0, hi = N_NODES;
    while (lo < hi) { int m = (lo + hi) >> 1; if (batch[m] < g) lo = m + 1; else hi = m; }
    int start = lo;
    hi = N_NODES;
    while (lo < hi) { int m = (lo + hi) >> 1; if (batch[m] < g + 1) lo = m + 1; else hi = m; }
    int end = lo;

    int l8 = (threadIdx.x & 15) << 3;
    int rg = threadIdx.x >> 4;
    float acc[8] = {0.f, 0.f, 0.f, 0.f, 0.f, 0.f, 0.f, 0.f};
    for (int i = start + rg; i < end; i += 16) {
        bf16x8 v = *reinterpret_cast<const bf16x8*>(H + (size_t)i * F + l8);
#pragma unroll
        for (int r = 0; r < 8; ++r) acc[r] += bf2f((unsigned short)v[r]);
    }
    __shared__ float sh[16][F];
    __shared__ float mean[F];
#pragma unroll
    for (int r = 0; r < 8; ++r) sh[rg][l8 + r] = acc[r];
    __syncthreads();
    if (threadIdx.x < F) {
        int f = threadIdx.x;
        float s = 0.f;
#pragma unroll
        for (int k = 0; k < 16; ++k) s += sh[k][f];
        float cnt = (float)(end - start);
        mean[f] = s / fmaxf(cnt, 1.f);
    }
    __syncthreads();
    if (threadIdx.x < N_CLASSES) {
        int c = threadIdx.x;
        float s = bl[c];
#pragma unroll 8
        for (int k = 0; k < F; ++k) s += mean[k] * Wl[c * F + k];
        out[g * N_CLASSES + c] = s;
    }
}

extern "C" void kernel_launch(void* const* d_in, const int* in_sizes, int n_in,
                              void* d_out, int out_size, void* d_ws, size_t ws_size,
                              hipStream_t stream)
{
    const float* x     = (const float*)d_in[0];
    const int*   edge  = (const int*)d_in[1];
    const int*   src   = edge;
    const int*   dst   = edge + N_EDGES;
    const int*   batch = (const int*)d_in[2];
    const float* W1r = (const float*)d_in[3];
    const float* b1  = (const float*)d_in[4];
    const float* W1o = (const float*)d_in[5];
    const float* W2r = (const float*)d_in[6];
    const float* b2  = (const float*)d_in[7];
    const float* W2o = (const float*)d_in[8];
    const float* W3r = (const float*)d_in[9];
    const float* b3  = (const float*)d_in[10];
    const float* W3o = (const float*)d_in[11];
    const float* Wl  = (const float*)d_in[12];
    const float* bl  = (const float*)d_in[13];
    float* out = (float*)d_out;

    char* ws = (char*)d_ws;
    const size_t fb = (size_t)NPAD * F * sizeof(unsigned short);   // 12.8 MB
    unsigned short* Xb  = (unsigned short*)ws;
    unsigned short* H1b = (unsigned short*)(ws + fb);
    unsigned short* H2b = (unsigned short*)(ws + 2 * fb);
    char* p = ws + 3 * fb;
    unsigned short* Wb = (unsigned short*)p;   // 6 contiguous FxF panels
    p += (size_t)6 * F * F * sizeof(unsigned short);
    int* deg     = (int*)p;              p += (size_t)N_NODES * sizeof(int);
    int* cursor  = (int*)p;              p += (size_t)N_NODES * sizeof(int);  // contiguous w/ deg
    int* off     = (int*)p;              p += (size_t)(N_NODES + 1) * sizeof(int);
    int* locEx   = (int*)p;              p += (size_t)N_NODES * sizeof(int);
    int* blockSum= (int*)p;              p += (size_t)256 * sizeof(int);
    int* csrP    = (int*)p;              p += (size_t)N_EDGES * sizeof(int);

    const int convBlocks = NPAD / 64;                                // 782
    const int prepBlocks = XCVT_BLOCKS + WCVT_BLOCKS + EDGE_BLOCKS;  // 8690

    // ---- prep (cvt + histogram) & compact packed CSR ----
    hipMemsetAsync(deg, 0, (size_t)2 * N_NODES * sizeof(int), stream);  // deg + cursor
    prep_kernel<<<prepBlocks, 256, 0, stream>>>(x, W1r, W1o, W2r, W2o, W3r, W3o,
                                                dst, Xb, Wb, deg);
    scanA_kernel<<<NB_SCAN, 256, 0, stream>>>(deg, locEx, blockSum);
    scanBC_kernel<<<NB_SCAN, 256, 0, stream>>>(locEx, blockSum, off);
    fillP_kernel<<<EDGE_BLOCKS, 256, 0, stream>>>(src, dst, off, cursor, csrP);

    // ---- 3 fused layers ----
    conv_fused<1><<<convBlocks, 256, 0, stream>>>(Xb,  off, csrP, Wb + 0 * F * F, Wb + 1 * F * F, b1, H1b);
    conv_fused<1><<<convBlocks, 256, 0, stream>>>(H1b, off, csrP, Wb + 2 * F * F, Wb + 3 * F * F, b2, H2b);
    conv_fused<0><<<convBlocks, 256, 0, stream>>>(H2b, off, csrP, Wb + 4 * F * F, Wb + 5 * F * F, b3, H1b);

    // ---- pool + head (fused) ----
    poolhead_kernel<<<N_GRAPHS, 256, 0, stream>>>(H1b, batch, Wl, bl, out);
}

// Round 11
// 268.347 us; speedup vs baseline: 6.2356x; 6.2356x over previous
//
#include <hip/hip_runtime.h>
#include <hip/hip_bf16.h>

#define N_NODES   50000
#define N_EDGES   600000
#define F         128
#define N_GRAPHS  64
#define N_CLASSES 10
#define NPAD      50048           // multiple of 64
#define NB_SCAN   196             // ceil(50000/256)
#define XCVT_BLOCKS 6250          // N_NODES*F/4/256
#define WCVT_BLOCKS 96            // 6*F*F/4/256
#define EDGE_BLOCKS 2344          // ceil(N_EDGES/256)

typedef __attribute__((ext_vector_type(8))) short bf16x8;
typedef __attribute__((ext_vector_type(4))) float f32x4;

static __device__ __forceinline__ unsigned short f2bf(float f) {
    __hip_bfloat16 h = __float2bfloat16(f);
    return *reinterpret_cast<unsigned short*>(&h);
}
static __device__ __forceinline__ float bf2f(unsigned short u) {
    return __uint_as_float(((unsigned)u) << 16);
}

// ================= prep: x->bf16, W->bf16, degree histogram — ONE dispatch =================
__global__ __launch_bounds__(256) void prep_kernel(
    const float* __restrict__ x,
    const float* __restrict__ W0, const float* __restrict__ W1,
    const float* __restrict__ W2, const float* __restrict__ W3,
    const float* __restrict__ W4, const float* __restrict__ W5,
    const int* __restrict__ dst,
    unsigned short* __restrict__ Xb, unsigned short* __restrict__ Wb,
    int* __restrict__ deg)
{
    int b = blockIdx.x;
    if (b < XCVT_BLOCKS) {
        int i = b * 256 + threadIdx.x;
        float4 v = reinterpret_cast<const float4*>(x)[i];
        ushort4 o;
        o.x = f2bf(v.x); o.y = f2bf(v.y); o.z = f2bf(v.z); o.w = f2bf(v.w);
        reinterpret_cast<ushort4*>(Xb)[i] = o;
    } else if (b < XCVT_BLOCKS + WCVT_BLOCKS) {
        const int PER = (F * F / 4) / 256;   // 16
        int bb  = b - XCVT_BLOCKS;
        int mat = bb / PER;
        int i   = (bb % PER) * 256 + threadIdx.x;
        const float* W = (mat == 0) ? W0 : (mat == 1) ? W1 : (mat == 2) ? W2
                       : (mat == 3) ? W3 : (mat == 4) ? W4 : W5;
        float4 v = reinterpret_cast<const float4*>(W)[i];
        ushort4 o;
        o.x = f2bf(v.x); o.y = f2bf(v.y); o.z = f2bf(v.z); o.w = f2bf(v.w);
        reinterpret_cast<ushort4*>(Wb + (size_t)mat * F * F)[i] = o;
    } else {
        int e = (b - XCVT_BLOCKS - WCVT_BLOCKS) * 256 + threadIdx.x;
        if (e < N_EDGES) atomicAdd(&deg[dst[e]], 1);
    }
}

// ---- hierarchical scan ----
__global__ __launch_bounds__(256) void scanA_kernel(
    const int* __restrict__ deg, int* __restrict__ locEx, int* __restrict__ blockSum)
{
    __shared__ int sh[256];
    int t = threadIdx.x;
    int idx = blockIdx.x * 256 + t;
    int v = (idx < N_NODES) ? deg[idx] : 0;
    sh[t] = v;
    __syncthreads();
#pragma unroll
    for (int d = 1; d < 256; d <<= 1) {
        int u = (t >= d) ? sh[t - d] : 0;
        __syncthreads();
        sh[t] += u;
        __syncthreads();
    }
    if (idx < N_NODES) locEx[idx] = sh[t] - v;
    if (t == 255) blockSum[blockIdx.x] = sh[255];
}

__global__ __launch_bounds__(256) void scanBC_kernel(
    const int* __restrict__ locEx, const int* __restrict__ blockSum,
    int* __restrict__ off)
{
    __shared__ int sh[256];
    int t = threadIdx.x;
    int v = (t < NB_SCAN) ? blockSum[t] : 0;
    sh[t] = v;
    __syncthreads();
#pragma unroll
    for (int d = 1; d < 256; d <<= 1) {
        int u = (t >= d) ? sh[t - d] : 0;
        __syncthreads();
        sh[t] += u;
        __syncthreads();
    }
    int myVal = blockSum[blockIdx.x];
    int base  = sh[blockIdx.x] - myVal;
    int idx = blockIdx.x * 256 + t;
    if (idx < N_NODES) off[idx] = locEx[idx] + base;
    if (blockIdx.x == 0 && t == 0) off[N_NODES] = sh[NB_SCAN - 1];
}

// fill compact CSR (src indices only; per-row segments contiguous)
__global__ __launch_bounds__(256) void fillP_kernel(
    const int* __restrict__ src, const int* __restrict__ dst,
    const int* __restrict__ off, int* __restrict__ cursor,
    int* __restrict__ csrP)
{
    int e = blockIdx.x * 256 + threadIdx.x;
    if (e >= N_EDGES) return;
    int d = dst[e];
    int slot = atomicAdd(&cursor[d], 1);
    csrP[off[d] + slot] = src[e];
}

// ================= fused gather + GraphConv via MFMA =================
// Phase 1: per-row neighbor sum (4 threads/row, 32 feats each), 2-edge batched
//          loads for MLP, fp32 reg accum -> bf16 XOR-swizzled LDS.
// Phase 2: H = [relu](AGG@Wrel^T + b + X@Wroot^T), 4 waves 2x2, tile 32x64.
template <int RELU>
__global__ __launch_bounds__(256) void conv_fused(
    const unsigned short* __restrict__ Xb,
    const int* __restrict__ off, const int* __restrict__ csrP,
    const unsigned short* __restrict__ Wrel, const unsigned short* __restrict__ Wroot,
    const float* __restrict__ brel, unsigned short* __restrict__ H)
{
    __shared__ char AsRaw[64 * 256];   // As[64][128] bf16, byte-XOR swizzled rows
    const int t = threadIdx.x;
    const int mBase = blockIdx.x * 64;

    // ---- phase 1 ----
    {
        const int r = t >> 2;            // 0..63
        const int q = t & 3;             // feature quarter
        int row = mBase + r;
        float acc[32];
#pragma unroll
        for (int i = 0; i < 32; ++i) acc[i] = 0.f;
        if (row < N_NODES) {
            int j0 = off[row], j1 = off[row + 1];
            const int* lst = csrP;
            const unsigned short* Xq = Xb + (size_t)q * 32;
            int j = j0;
            for (; j + 2 <= j1; j += 2) {
                int sa = lst[j], sb = lst[j + 1];
                const bf16x8* pa = reinterpret_cast<const bf16x8*>(Xq + (size_t)sa * F);
                const bf16x8* pb = reinterpret_cast<const bf16x8*>(Xq + (size_t)sb * F);
                bf16x8 va0 = pa[0], va1 = pa[1], va2 = pa[2], va3 = pa[3];
                bf16x8 vb0 = pb[0], vb1 = pb[1], vb2 = pb[2], vb3 = pb[3];
#pragma unroll
                for (int e = 0; e < 8; ++e) {
                    acc[e]      += bf2f((unsigned short)va0[e]) + bf2f((unsigned short)vb0[e]);
                    acc[8 + e]  += bf2f((unsigned short)va1[e]) + bf2f((unsigned short)vb1[e]);
                    acc[16 + e] += bf2f((unsigned short)va2[e]) + bf2f((unsigned short)vb2[e]);
                    acc[24 + e] += bf2f((unsigned short)va3[e]) + bf2f((unsigned short)vb3[e]);
                }
            }
            if (j < j1) {
                int sa = lst[j];
                const bf16x8* pa = reinterpret_cast<const bf16x8*>(Xq + (size_t)sa * F);
                bf16x8 va0 = pa[0], va1 = pa[1], va2 = pa[2], va3 = pa[3];
#pragma unroll
                for (int e = 0; e < 8; ++e) {
                    acc[e]      += bf2f((unsigned short)va0[e]);
                    acc[8 + e]  += bf2f((unsigned short)va1[e]);
                    acc[16 + e] += bf2f((unsigned short)va2[e]);
                    acc[24 + e] += bf2f((unsigned short)va3[e]);
                }
            }
        }
#pragma unroll
        for (int cc = 0; cc < 4; ++cc) {
            bf16x8 o;
#pragma unroll
            for (int e = 0; e < 8; ++e) o[e] = (short)f2bf(acc[cc * 8 + e]);
            int bytecol = (q * 64 + cc * 16) ^ ((r & 7) << 4);
            *reinterpret_cast<bf16x8*>(AsRaw + r * 256 + bytecol) = o;
        }
    }
    __syncthreads();

    // ---- phase 2: MFMA, 4 waves in 2x2, wave tile 32x64 ----
    const int wave = t >> 6;
    const int lane = t & 63;
    const int wm = wave >> 1, wn = wave & 1;
    const int m0l = wm * 32;
    const int n0  = wn * 64;
    const int lrow = lane & 15;
    const int lk8  = (lane >> 4) << 3;

    f32x4 acc[2][4];
#pragma unroll
    for (int mi = 0; mi < 2; ++mi)
#pragma unroll
        for (int ni = 0; ni < 4; ++ni)
            acc[mi][ni] = (f32x4){0.f, 0.f, 0.f, 0.f};

#pragma unroll
    for (int p = 0; p < 2; ++p) {
        const unsigned short* W = p ? Wroot : Wrel;
#pragma unroll
        for (int ks = 0; ks < 4; ++ks) {
            int k0 = ks * 32 + lk8;
            bf16x8 a[2], b[4];
#pragma unroll
            for (int mi = 0; mi < 2; ++mi) {
                int rl = m0l + mi * 16 + lrow;
                if (p == 0) {
                    int bytecol = (k0 * 2) ^ ((rl & 7) << 4);
                    a[mi] = *reinterpret_cast<const bf16x8*>(AsRaw + rl * 256 + bytecol);
                } else {
                    a[mi] = *reinterpret_cast<const bf16x8*>(
                        Xb + (size_t)(mBase + rl) * F + k0);
                }
            }
#pragma unroll
            for (int ni = 0; ni < 4; ++ni)
                b[ni] = *reinterpret_cast<const bf16x8*>(
                    W + (size_t)(n0 + ni * 16 + lrow) * F + k0);
#pragma unroll
            for (int mi = 0; mi < 2; ++mi)
#pragma unroll
                for (int ni = 0; ni < 4; ++ni)
                    acc[mi][ni] = __builtin_amdgcn_mfma_f32_16x16x32_bf16(
                        a[mi], b[ni], acc[mi][ni], 0, 0, 0);
        }
    }

    const int r0 = (lane >> 4) << 2;   // C/D: row = (lane>>4)*4 + reg
#pragma unroll
    for (int ni = 0; ni < 4; ++ni) {
        int col = n0 + ni * 16 + lrow;
        float bb = brel[col];
#pragma unroll
        for (int mi = 0; mi < 2; ++mi) {
#pragma unroll
            for (int r = 0; r < 4; ++r) {
                int row = mBase + m0l + mi * 16 + r0 + r;
                if (row < N_NODES) {
                    float v = acc[mi][ni][r] + bb;
                    if (RELU) v = fmaxf(v, 0.f);
                    H[(size_t)row * F + col] = f2bf(v);
                }
            }
        }
    }
}

// ================= mean pool + classifier head fused =================
__global__ __launch_bounds__(256) void poolhead_kernel(
    const unsigned short* __restrict__ H, const int* __restrict__ batch,
    const float* __restrict__ Wl, const float* __restrict__ bl,
    float* __restrict__ out)
{
    int g = blockIdx.x;
    int lo = 0, hi = N_NODES;
    while (lo < hi) { int m = (lo + hi) >> 1; if (batch[m] < g) lo = m + 1; else hi = m; }
    int start = lo;
    hi = N_NODES;
    while (lo < hi) { int m = (lo + hi) >> 1; if (batch[m] < g + 1) lo = m + 1; else hi = m; }
    int end = lo;

    int l8 = (threadIdx.x & 15) << 3;
    int rg = threadIdx.x >> 4;
    float acc[8] = {0.f, 0.f, 0.f, 0.f, 0.f, 0.f, 0.f, 0.f};
    for (int i = start + rg; i < end; i += 16) {
        bf16x8 v = *reinterpret_cast<const bf16x8*>(H + (size_t)i * F + l8);
#pragma unroll
        for (int r = 0; r < 8; ++r) acc[r] += bf2f((unsigned short)v[r]);
    }
    __shared__ float sh[16][F];
    __shared__ float mean[F];
#pragma unroll
    for (int r = 0; r < 8; ++r) sh[rg][l8 + r] = acc[r];
    __syncthreads();
    if (threadIdx.x < F) {
        int f = threadIdx.x;
        float s = 0.f;
#pragma unroll
        for (int k = 0; k < 16; ++k) s += sh[k][f];
        float cnt = (float)(end - start);
        mean[f] = s / fmaxf(cnt, 1.f);
    }
    __syncthreads();
    if (threadIdx.x < N_CLASSES) {
        int c = threadIdx.x;
        float s = bl[c];
#pragma unroll 8
        for (int k = 0; k < F; ++k) s += mean[k] * Wl[c * F + k];
        out[g * N_CLASSES + c] = s;
    }
}

extern "C" void kernel_launch(void* const* d_in, const int* in_sizes, int n_in,
                              void* d_out, int out_size, void* d_ws, size_t ws_size,
                              hipStream_t stream)
{
    const float* x     = (const float*)d_in[0];
    const int*   edge  = (const int*)d_in[1];
    const int*   src   = edge;
    const int*   dst   = edge + N_EDGES;
    const int*   batch = (const int*)d_in[2];
    const float* W1r = (const float*)d_in[3];
    const float* b1  = (const float*)d_in[4];
    const float* W1o = (const float*)d_in[5];
    const float* W2r = (const float*)d_in[6];
    const float* b2  = (const float*)d_in[7];
    const float* W2o = (const float*)d_in[8];
    const float* W3r = (const float*)d_in[9];
    const float* b3  = (const float*)d_in[10];
    const float* W3o = (const float*)d_in[11];
    const float* Wl  = (const float*)d_in[12];
    const float* bl  = (const float*)d_in[13];
    float* out = (float*)d_out;

    char* ws = (char*)d_ws;
    const size_t fb = (size_t)NPAD * F * sizeof(unsigned short);   // 12.8 MB
    unsigned short* Xb  = (unsigned short*)ws;
    unsigned short* H1b = (unsigned short*)(ws + fb);
    unsigned short* H2b = (unsigned short*)(ws + 2 * fb);
    char* p = ws + 3 * fb;
    unsigned short* Wb = (unsigned short*)p;   // 6 contiguous FxF panels
    p += (size_t)6 * F * F * sizeof(unsigned short);
    int* deg     = (int*)p;              p += (size_t)N_NODES * sizeof(int);
    int* cursor  = (int*)p;              p += (size_t)N_NODES * sizeof(int);  // contiguous w/ deg
    int* off     = (int*)p;              p += (size_t)(N_NODES + 1) * sizeof(int);
    int* locEx   = (int*)p;              p += (size_t)N_NODES * sizeof(int);
    int* blockSum= (int*)p;              p += (size_t)256 * sizeof(int);
    int* csrP    = (int*)p;              p += (size_t)N_EDGES * sizeof(int);

    const int convBlocks = NPAD / 64;                                // 782
    const int prepBlocks = XCVT_BLOCKS + WCVT_BLOCKS + EDGE_BLOCKS;  // 8690

    // ---- prep (cvt + histogram) & compact CSR ----
    hipMemsetAsync(deg, 0, (size_t)2 * N_NODES * sizeof(int), stream);  // deg + cursor
    prep_kernel<<<prepBlocks, 256, 0, stream>>>(x, W1r, W1o, W2r, W2o, W3r, W3o,
                                                dst, Xb, Wb, deg);
    scanA_kernel<<<NB_SCAN, 256, 0, stream>>>(deg, locEx, blockSum);
    scanBC_kernel<<<NB_SCAN, 256, 0, stream>>>(locEx, blockSum, off);
    fillP_kernel<<<EDGE_BLOCKS, 256, 0, stream>>>(src, dst, off, cursor, csrP);

    // ---- 3 fused layers ----
    conv_fused<1><<<convBlocks, 256, 0, stream>>>(Xb,  off, csrP, Wb + 0 * F * F, Wb + 1 * F * F, b1, H1b);
    conv_fused<1><<<convBlocks, 256, 0, stream>>>(H1b, off, csrP, Wb + 2 * F * F, Wb + 3 * F * F, b2, H2b);
    conv_fused<0><<<convBlocks, 256, 0, stream>>>(H2b, off, csrP, Wb + 4 * F * F, Wb + 5 * F * F, b3, H1b);

    // ---- pool + head (fused) ----
    poolhead_kernel<<<N_GRAPHS, 256, 0, stream>>>(H1b, batch, Wl, bl, out);
}

// Round 12
// 241.297 us; speedup vs baseline: 6.9346x; 1.1121x over previous
//
#include <hip/hip_runtime.h>
#include <hip/hip_bf16.h>

#define N_NODES   50000
#define N_EDGES   600000
#define F         128
#define N_GRAPHS  64
#define N_CLASSES 10
#define NPAD      50048           // multiple of 64
#define NB_SCAN   196             // ceil(50000/256)
#define XCVT_BLOCKS 6250          // N_NODES*F/4/256
#define WCVT_BLOCKS 96            // 6*F*F/4/256
#define EDGE_BLOCKS 2344          // ceil(N_EDGES/256)

typedef __attribute__((ext_vector_type(8))) short bf16x8;
typedef __attribute__((ext_vector_type(4))) float f32x4;

static __device__ __forceinline__ unsigned short f2bf(float f) {
    __hip_bfloat16 h = __float2bfloat16(f);
    return *reinterpret_cast<unsigned short*>(&h);
}
static __device__ __forceinline__ float bf2f(unsigned short u) {
    return __uint_as_float(((unsigned)u) << 16);
}

// ================= prep: x->bf16, W->bf16, degree histogram — ONE dispatch =================
__global__ __launch_bounds__(256) void prep_kernel(
    const float* __restrict__ x,
    const float* __restrict__ W0, const float* __restrict__ W1,
    const float* __restrict__ W2, const float* __restrict__ W3,
    const float* __restrict__ W4, const float* __restrict__ W5,
    const int* __restrict__ dst,
    unsigned short* __restrict__ Xb, unsigned short* __restrict__ Wb,
    int* __restrict__ deg)
{
    int b = blockIdx.x;
    if (b < XCVT_BLOCKS) {
        int i = b * 256 + threadIdx.x;
        float4 v = reinterpret_cast<const float4*>(x)[i];
        ushort4 o;
        o.x = f2bf(v.x); o.y = f2bf(v.y); o.z = f2bf(v.z); o.w = f2bf(v.w);
        reinterpret_cast<ushort4*>(Xb)[i] = o;
    } else if (b < XCVT_BLOCKS + WCVT_BLOCKS) {
        const int PER = (F * F / 4) / 256;   // 16
        int bb  = b - XCVT_BLOCKS;
        int mat = bb / PER;
        int i   = (bb % PER) * 256 + threadIdx.x;
        const float* W = (mat == 0) ? W0 : (mat == 1) ? W1 : (mat == 2) ? W2
                       : (mat == 3) ? W3 : (mat == 4) ? W4 : W5;
        float4 v = reinterpret_cast<const float4*>(W)[i];
        ushort4 o;
        o.x = f2bf(v.x); o.y = f2bf(v.y); o.z = f2bf(v.z); o.w = f2bf(v.w);
        reinterpret_cast<ushort4*>(Wb + (size_t)mat * F * F)[i] = o;
    } else {
        int e = (b - XCVT_BLOCKS - WCVT_BLOCKS) * 256 + threadIdx.x;
        if (e < N_EDGES) atomicAdd(&deg[dst[e]], 1);
    }
}

// ---- hierarchical scan ----
__global__ __launch_bounds__(256) void scanA_kernel(
    const int* __restrict__ deg, int* __restrict__ locEx, int* __restrict__ blockSum)
{
    __shared__ int sh[256];
    int t = threadIdx.x;
    int idx = blockIdx.x * 256 + t;
    int v = (idx < N_NODES) ? deg[idx] : 0;
    sh[t] = v;
    __syncthreads();
#pragma unroll
    for (int d = 1; d < 256; d <<= 1) {
        int u = (t >= d) ? sh[t - d] : 0;
        __syncthreads();
        sh[t] += u;
        __syncthreads();
    }
    if (idx < N_NODES) locEx[idx] = sh[t] - v;
    if (t == 255) blockSum[blockIdx.x] = sh[255];
}

__global__ __launch_bounds__(256) void scanBC_kernel(
    const int* __restrict__ locEx, const int* __restrict__ blockSum,
    int* __restrict__ off)
{
    __shared__ int sh[256];
    int t = threadIdx.x;
    int v = (t < NB_SCAN) ? blockSum[t] : 0;
    sh[t] = v;
    __syncthreads();
#pragma unroll
    for (int d = 1; d < 256; d <<= 1) {
        int u = (t >= d) ? sh[t - d] : 0;
        __syncthreads();
        sh[t] += u;
        __syncthreads();
    }
    int myVal = blockSum[blockIdx.x];
    int base  = sh[blockIdx.x] - myVal;
    int idx = blockIdx.x * 256 + t;
    if (idx < N_NODES) off[idx] = locEx[idx] + base;
    if (blockIdx.x == 0 && t == 0) off[N_NODES] = sh[NB_SCAN - 1];
}

// fill compact CSR (ushort src indices; per-row segments contiguous)
__global__ __launch_bounds__(256) void fillP_kernel(
    const int* __restrict__ src, const int* __restrict__ dst,
    const int* __restrict__ off, int* __restrict__ cursor,
    unsigned short* __restrict__ csrP)
{
    int e = blockIdx.x * 256 + threadIdx.x;
    if (e >= N_EDGES) return;
    int d = dst[e];
    int slot = atomicAdd(&cursor[d], 1);
    csrP[off[d] + slot] = (unsigned short)src[e];
}

// ================= fused gather + GraphConv via MFMA =================
// Phase 1: 16 lanes/row (lane covers 8 feats = 16B) -> each edge read is one
//          fully-coalesced 256B wave-group access; 4-edge batching; fp32 reg
//          accum -> bf16 XOR-swizzled LDS. 4 row-iterations per thread (BM=64).
// Phase 2: H = [relu](AGG@Wrel^T + b + X@Wroot^T), 4 waves 2x2, tile 32x64.
template <int RELU>
__global__ __launch_bounds__(256) void conv_fused(
    const unsigned short* __restrict__ Xb,
    const int* __restrict__ off, const unsigned short* __restrict__ csrP,
    const unsigned short* __restrict__ Wrel, const unsigned short* __restrict__ Wroot,
    const float* __restrict__ brel, unsigned short* __restrict__ H)
{
    __shared__ char AsRaw[64 * 256];   // As[64][128] bf16, byte-XOR swizzled rows
    const int t = threadIdx.x;
    const int mBase = blockIdx.x * 64;

    // ---- phase 1: coalesced gather, 16 lanes per row ----
    {
        const int sub = t & 15;          // 16B chunk: feats sub*8 .. sub*8+7
        const int rr  = t >> 4;          // 0..15
        const unsigned short* Xq = Xb + sub * 8;
#pragma unroll
        for (int it = 0; it < 4; ++it) {
            int r   = it * 16 + rr;      // 0..63
            int row = mBase + r;
            float acc[8] = {0.f, 0.f, 0.f, 0.f, 0.f, 0.f, 0.f, 0.f};
            if (row < N_NODES) {
                int j  = off[row];
                int j1 = off[row + 1];
                for (; j + 4 <= j1; j += 4) {
                    int s0 = csrP[j], s1 = csrP[j + 1];
                    int s2 = csrP[j + 2], s3 = csrP[j + 3];
                    bf16x8 v0 = *reinterpret_cast<const bf16x8*>(Xq + (size_t)s0 * F);
                    bf16x8 v1 = *reinterpret_cast<const bf16x8*>(Xq + (size_t)s1 * F);
                    bf16x8 v2 = *reinterpret_cast<const bf16x8*>(Xq + (size_t)s2 * F);
                    bf16x8 v3 = *reinterpret_cast<const bf16x8*>(Xq + (size_t)s3 * F);
#pragma unroll
                    for (int e = 0; e < 8; ++e) {
                        acc[e] += (bf2f((unsigned short)v0[e]) + bf2f((unsigned short)v1[e]))
                                + (bf2f((unsigned short)v2[e]) + bf2f((unsigned short)v3[e]));
                    }
                }
                for (; j < j1; ++j) {
                    int s0 = csrP[j];
                    bf16x8 v0 = *reinterpret_cast<const bf16x8*>(Xq + (size_t)s0 * F);
#pragma unroll
                    for (int e = 0; e < 8; ++e) acc[e] += bf2f((unsigned short)v0[e]);
                }
            }
            bf16x8 o;
#pragma unroll
            for (int e = 0; e < 8; ++e) o[e] = (short)f2bf(acc[e]);
            int bytecol = (sub * 16) ^ ((r & 7) << 4);
            *reinterpret_cast<bf16x8*>(AsRaw + r * 256 + bytecol) = o;
        }
    }
    __syncthreads();

    // ---- phase 2: MFMA, 4 waves in 2x2, wave tile 32x64 ----
    const int wave = t >> 6;
    const int lane = t & 63;
    const int wm = wave >> 1, wn = wave & 1;
    const int m0l = wm * 32;
    const int n0  = wn * 64;
    const int lrow = lane & 15;
    const int lk8  = (lane >> 4) << 3;

    f32x4 acc[2][4];
#pragma unroll
    for (int mi = 0; mi < 2; ++mi)
#pragma unroll
        for (int ni = 0; ni < 4; ++ni)
            acc[mi][ni] = (f32x4){0.f, 0.f, 0.f, 0.f};

#pragma unroll
    for (int p = 0; p < 2; ++p) {
        const unsigned short* W = p ? Wroot : Wrel;
#pragma unroll
        for (int ks = 0; ks < 4; ++ks) {
            int k0 = ks * 32 + lk8;
            bf16x8 a[2], b[4];
#pragma unroll
            for (int mi = 0; mi < 2; ++mi) {
                int rl = m0l + mi * 16 + lrow;
                if (p == 0) {
                    int bytecol = (k0 * 2) ^ ((rl & 7) << 4);
                    a[mi] = *reinterpret_cast<const bf16x8*>(AsRaw + rl * 256 + bytecol);
                } else {
                    a[mi] = *reinterpret_cast<const bf16x8*>(
                        Xb + (size_t)(mBase + rl) * F + k0);
                }
            }
#pragma unroll
            for (int ni = 0; ni < 4; ++ni)
                b[ni] = *reinterpret_cast<const bf16x8*>(
                    W + (size_t)(n0 + ni * 16 + lrow) * F + k0);
#pragma unroll
            for (int mi = 0; mi < 2; ++mi)
#pragma unroll
                for (int ni = 0; ni < 4; ++ni)
                    acc[mi][ni] = __builtin_amdgcn_mfma_f32_16x16x32_bf16(
                        a[mi], b[ni], acc[mi][ni], 0, 0, 0);
        }
    }

    const int r0 = (lane >> 4) << 2;   // C/D: row = (lane>>4)*4 + reg
#pragma unroll
    for (int ni = 0; ni < 4; ++ni) {
        int col = n0 + ni * 16 + lrow;
        float bb = brel[col];
#pragma unroll
        for (int mi = 0; mi < 2; ++mi) {
#pragma unroll
            for (int r = 0; r < 4; ++r) {
                int row = mBase + m0l + mi * 16 + r0 + r;
                if (row < N_NODES) {
                    float v = acc[mi][ni][r] + bb;
                    if (RELU) v = fmaxf(v, 0.f);
                    H[(size_t)row * F + col] = f2bf(v);
                }
            }
        }
    }
}

// ================= mean pool + classifier head fused =================
__global__ __launch_bounds__(256) void poolhead_kernel(
    const unsigned short* __restrict__ H, const int* __restrict__ batch,
    const float* __restrict__ Wl, const float* __restrict__ bl,
    float* __restrict__ out)
{
    int g = blockIdx.x;
    int lo = 0, hi = N_NODES;
    while (lo < hi) { int m = (lo + hi) >> 1; if (batch[m] < g) lo = m + 1; else hi = m; }
    int start = lo;
    hi = N_NODES;
    while (lo < hi) { int m = (lo + hi) >> 1; if (batch[m] < g + 1) lo = m + 1; else hi = m; }
    int end = lo;

    int l8 = (threadIdx.x & 15) << 3;
    int rg = threadIdx.x >> 4;
    float acc[8] = {0.f, 0.f, 0.f, 0.f, 0.f, 0.f, 0.f, 0.f};
    for (int i = start + rg; i < end; i += 16) {
        bf16x8 v = *reinterpret_cast<const bf16x8*>(H + (size_t)i * F + l8);
#pragma unroll
        for (int r = 0; r < 8; ++r) acc[r] += bf2f((unsigned short)v[r]);
    }
    __shared__ float sh[16][F];
    __shared__ float mean[F];
#pragma unroll
    for (int r = 0; r < 8; ++r) sh[rg][l8 + r] = acc[r];
    __syncthreads();
    if (threadIdx.x < F) {
        int f = threadIdx.x;
        float s = 0.f;
#pragma unroll
        for (int k = 0; k < 16; ++k) s += sh[k][f];
        float cnt = (float)(end - start);
        mean[f] = s / fmaxf(cnt, 1.f);
    }
    __syncthreads();
    if (threadIdx.x < N_CLASSES) {
        int c = threadIdx.x;
        float s = bl[c];
#pragma unroll 8
        for (int k = 0; k < F; ++k) s += mean[k] * Wl[c * F + k];
        out[g * N_CLASSES + c] = s;
    }
}

extern "C" void kernel_launch(void* const* d_in, const int* in_sizes, int n_in,
                              void* d_out, int out_size, void* d_ws, size_t ws_size,
                              hipStream_t stream)
{
    const float* x     = (const float*)d_in[0];
    const int*   edge  = (const int*)d_in[1];
    const int*   src   = edge;
    const int*   dst   = edge + N_EDGES;
    const int*   batch = (const int*)d_in[2];
    const float* W1r = (const float*)d_in[3];
    const float* b1  = (const float*)d_in[4];
    const float* W1o = (const float*)d_in[5];
    const float* W2r = (const float*)d_in[6];
    const float* b2  = (const float*)d_in[7];
    const float* W2o = (const float*)d_in[8];
    const float* W3r = (const float*)d_in[9];
    const float* b3  = (const float*)d_in[10];
    const float* W3o = (const float*)d_in[11];
    const float* Wl  = (const float*)d_in[12];
    const float* bl  = (const float*)d_in[13];
    float* out = (float*)d_out;

    char* ws = (char*)d_ws;
    const size_t fb = (size_t)NPAD * F * sizeof(unsigned short);   // 12.8 MB
    unsigned short* Xb  = (unsigned short*)ws;
    unsigned short* H1b = (unsigned short*)(ws + fb);
    unsigned short* H2b = (unsigned short*)(ws + 2 * fb);
    char* p = ws + 3 * fb;
    unsigned short* Wb = (unsigned short*)p;   // 6 contiguous FxF panels
    p += (size_t)6 * F * F * sizeof(unsigned short);
    int* deg     = (int*)p;              p += (size_t)N_NODES * sizeof(int);
    int* cursor  = (int*)p;              p += (size_t)N_NODES * sizeof(int);  // contiguous w/ deg
    int* off     = (int*)p;              p += (size_t)(N_NODES + 1) * sizeof(int);
    int* locEx   = (int*)p;              p += (size_t)N_NODES * sizeof(int);
    int* blockSum= (int*)p;              p += (size_t)256 * sizeof(int);
    unsigned short* csrP = (unsigned short*)p;

    const int convBlocks = NPAD / 64;                                // 782
    const int prepBlocks = XCVT_BLOCKS + WCVT_BLOCKS + EDGE_BLOCKS;  // 8690

    // ---- prep (cvt + histogram) & compact CSR ----
    hipMemsetAsync(deg, 0, (size_t)2 * N_NODES * sizeof(int), stream);  // deg + cursor
    prep_kernel<<<prepBlocks, 256, 0, stream>>>(x, W1r, W1o, W2r, W2o, W3r, W3o,
                                                dst, Xb, Wb, deg);
    scanA_kernel<<<NB_SCAN, 256, 0, stream>>>(deg, locEx, blockSum);
    scanBC_kernel<<<NB_SCAN, 256, 0, stream>>>(locEx, blockSum, off);
    fillP_kernel<<<EDGE_BLOCKS, 256, 0, stream>>>(src, dst, off, cursor, csrP);

    // ---- 3 fused layers ----
    conv_fused<1><<<convBlocks, 256, 0, stream>>>(Xb,  off, csrP, Wb + 0 * F * F, Wb + 1 * F * F, b1, H1b);
    conv_fused<1><<<convBlocks, 256, 0, stream>>>(H1b, off, csrP, Wb + 2 * F * F, Wb + 3 * F * F, b2, H2b);
    conv_fused<0><<<convBlocks, 256, 0, stream>>>(H2b, off, csrP, Wb + 4 * F * F, Wb + 5 * F * F, b3, H1b);

    // ---- pool + head (fused) ----
    poolhead_kernel<<<N_GRAPHS, 256, 0, stream>>>(H1b, batch, Wl, bl, out);
}